// Round 11
// baseline (143.062 us; speedup 1.0000x reference)
//
#include <hip/hip_runtime.h>

#define NQ      10
#define NLAYERS 4
#define D_IN    784
#define BLOCK   256   // 4 waves per workgroup, ONE state per wave, amp-pair pk packing.
// R24: single knob on the unchanged R23 kernel: waves_per_eu(2,8) -> (6,8).
// Unified residency model (R13-R23 data): occupancy tracks the waves_per_eu MIN
// ((8,8)->56%, (6,8)->46%, (5,8)->41%, (4,8)->36%, (2,8)->34%) => the min sets register
// ALLOCATION (512/min) and HW computes residency from ALLOCATED regs, not used ones.
// R23's appetite is ~64 (VGPR_Count=64 under a loose 256 budget) -- first kernel of the
// session that fits a tight budget. (6,8) = 85-reg allocation >= 64 appetite + headroom
// -> 6 waves/SIMD cap, no spill (unlike R19: same knob at ~120 appetite -> 45MB spill).
// Predicted: WRITE ~320KB (tripwire; spill -> revert), occ 34->50-65, busy 67->78-85,
// dur 77 -> 60-66us. Flat+clean -> structural floor; revert & stop next.
// R23 (kept): merged boundary diagonals D_phi(l+1) o Ring o D_omega(l) = Ring o D'
// with 64-entry LDS lane trig + 4-parity-variant reg tables; in-loop sincos = 0;
// Rot = D_omega * RY * D_phi factorization; real RY gates; last D_omega skipped;
// embedding = product-state init; ring CNOT(9,0) folded into ry0_fused / measurement.
// LOCKED: reductions use plain __shfl_xor only (R8 DPP reductions diverged across graph
// replays). DPP confined to full-exec lane exchanges (stable since R4).

// Amplitude index i (10 bits): lane bits 9..4 (q0..q5 = lane&32..lane&1),
// array-index bits 3..1 (q6,q7,q8 = a&4,a&2,a&1), component bit 0 (q9 = f2 comp).

typedef __attribute__((ext_vector_type(2))) float f2;

__device__ __forceinline__ f2 sp(float v) { f2 r; r.x = v; r.y = v; return r; }
__device__ __forceinline__ f2 swapc(f2 v) { return __builtin_shufflevector(v, v, 1, 0); }

// ---- lane exchange: xor LB, VALU pipe where possible ----
template<int LB>
__device__ __forceinline__ float lx(float v) {
    if constexpr (LB == 1) {        // quad_perm [1,0,3,2]
        return __int_as_float(__builtin_amdgcn_update_dpp(
            0, __float_as_int(v), 0xB1, 0xF, 0xF, false));
    } else if constexpr (LB == 2) { // quad_perm [2,3,0,1]
        return __int_as_float(__builtin_amdgcn_update_dpp(
            0, __float_as_int(v), 0x4E, 0xF, 0xF, false));
    } else if constexpr (LB == 8) { // row_ror:8 within 16 == xor 8 (VALU)
        return __int_as_float(__builtin_amdgcn_update_dpp(
            0, __float_as_int(v), 0x128, 0xF, 0xF, false));
    } else {
        return __shfl_xor(v, LB, 64);   // LB==4: DS pipe (no VALU equivalent)
    }
}

template<int LB>
__device__ __forceinline__ f2 lx2(f2 v) {
    f2 r; r.x = lx<LB>(v.x); r.y = lx<LB>(v.y); return r;
}

// ---- permlane pair swap (VALU pipe) ----
template<int HALF>
__device__ __forceinline__ void plswap(f2 &d, f2 &s) {
    if constexpr (HALF == 32) {
        auto rx = __builtin_amdgcn_permlane32_swap(__float_as_int(d.x), __float_as_int(s.x), false, false);
        auto ry = __builtin_amdgcn_permlane32_swap(__float_as_int(d.y), __float_as_int(s.y), false, false);
        d.x = __int_as_float(rx[0]); s.x = __int_as_float(rx[1]);
        d.y = __int_as_float(ry[0]); s.y = __int_as_float(ry[1]);
    } else {
        auto rx = __builtin_amdgcn_permlane16_swap(__float_as_int(d.x), __float_as_int(s.x), false, false);
        auto ry = __builtin_amdgcn_permlane16_swap(__float_as_int(d.y), __float_as_int(s.y), false, false);
        d.x = __int_as_float(rx[0]); s.x = __int_as_float(rx[1]);
        d.y = __int_as_float(ry[0]); s.y = __int_as_float(ry[1]);
    }
}

// ---- real RY on lane bit 32/16 via permlane pair-processing ----
template<int HALF>
__device__ __forceinline__ void ry_pl(f2 (&re)[8], f2 (&im)[8], float c, float s) {
#pragma unroll
    for (int a = 0; a < 8; a += 2) {
        f2 ur = re[a], vr = re[a + 1], ui = im[a], vi = im[a + 1];
        plswap<HALF>(ur, vr); plswap<HALF>(ui, vi);
        f2 nur = sp(c)*ur - sp(s)*vr;   f2 nui = sp(c)*ui - sp(s)*vi;
        f2 nvr = sp(s)*ur + sp(c)*vr;   f2 nvi = sp(s)*ui + sp(c)*vi;
        plswap<HALF>(nur, nvr); plswap<HALF>(nui, nvi);
        re[a] = nur; re[a + 1] = nvr; im[a] = nui; im[a + 1] = nvi;
    }
}

// ---- real RY on q0 (lane bit 32) with pending CNOT(ctrl=comp, tgt=bit32) consumed. ----
__device__ __forceinline__ void ry0_fused(f2 (&re)[8], f2 (&im)[8], float c, float s) {
    f2 K1, K2, K3, K4;
    K1.x =  c; K1.y = -s;   K2.x = -s; K2.y =  c;
    K3.x =  s; K3.y =  c;   K4.x =  c; K4.y =  s;
#pragma unroll
    for (int a = 0; a < 8; a += 2) {
        f2 ur = re[a], vr = re[a + 1], ui = im[a], vi = im[a + 1];
        plswap<32>(ur, vr); plswap<32>(ui, vi);
        f2 nur = K1*ur + K2*vr;   f2 nui = K1*ui + K2*vi;
        f2 nvr = K3*ur + K4*vr;   f2 nvi = K3*ui + K4*vi;
        plswap<32>(nur, nvr); plswap<32>(nui, nvi);
        re[a] = nur; re[a + 1] = nvr; im[a] = nui; im[a + 1] = nvi;
    }
}

// ---- real RY on lane bit LB (8,4,2,1): exchange + 4 pk per reg ----
template<int LB>
__device__ __forceinline__ void ry_lane(f2 (&re)[8], f2 (&im)[8], int lane, float c, float s) {
    const float o = (lane & LB) ? s : -s;   // lo: u' = c*u - s*v ; hi: v' = c*v + s*u
#pragma unroll
    for (int a = 0; a < 8; a++) {
        f2 ore = lx2<LB>(re[a]);
        f2 oim = lx2<LB>(im[a]);
        re[a] = sp(c)*re[a] + sp(o)*ore;
        im[a] = sp(c)*im[a] + sp(o)*oim;
    }
}

// ---- real RY on array-index bit MB (4,2,1): 8 pk per pair ----
template<int MB>
__device__ __forceinline__ void ry_reg(f2 (&re)[8], f2 (&im)[8], float c, float s) {
#pragma unroll
    for (int a = 0; a < 8; a++) {
        if (!(a & MB)) {
            const int a1 = a | MB;
            f2 r0 = re[a], r1 = re[a1], i0 = im[a], i1 = im[a1];
            re[a]  = sp(c)*r0 - sp(s)*r1;   re[a1] = sp(s)*r0 + sp(c)*r1;
            im[a]  = sp(c)*i0 - sp(s)*i1;   im[a1] = sp(s)*i0 + sp(c)*i1;
        }
    }
}

// ---- real RY on the component bit (q9): swapc + 4 pk per reg ----
__device__ __forceinline__ void ry_comp(f2 (&re)[8], f2 (&im)[8], float c, float s) {
    f2 Ks; Ks.x = -s; Ks.y = s;
#pragma unroll
    for (int a = 0; a < 8; a++) {
        f2 sre = swapc(re[a]), sim = swapc(im[a]);
        re[a] = sp(c)*re[a] + Ks*sre;
        im[a] = sp(c)*im[a] + Ks*sim;
    }
}

// ---- table-driven diagonal: factor = e^{i*lane_phase} * e^{i*table_phase[a]}.
// lp = (cos,sin) of the lane phase (from LDS); DC/DS = cos/sin reg tables (comp-packed).
__device__ __forceinline__ void diag_tbl(f2 (&re)[8], f2 (&im)[8], f2 lp,
                                         const f2* DC, const f2* DS) {
    f2 cl = sp(lp.x), sl = sp(lp.y);
#pragma unroll
    for (int a = 0; a < 8; a++) {
        f2 cr = cl*DC[a] - sl*DS[a];      // cos(lane+table)
        f2 ci = cl*DS[a] + sl*DC[a];      // sin(lane+table)
        f2 nr = cr*re[a] - ci*im[a];
        f2 ni = cr*im[a] + ci*re[a];
        re[a] = nr; im[a] = ni;
    }
}

__device__ __forceinline__ void swapf2(f2 &a, f2 &b) { f2 t = a; a = b; b = t; }

// ---- CNOT ring: Gray bpermute (q0..q5 chain), (5,6) cndmask, renames, (8,9) comp swap.
// (9,0) NOT applied: folded into next layer's ry0_fused or measurement signs. ----
__device__ __forceinline__ void ring(f2 (&re)[8], f2 (&im)[8], int lane, int bidx) {
#pragma unroll
    for (int a = 0; a < 8; a++) {
        re[a].x = __int_as_float(__builtin_amdgcn_ds_bpermute(bidx, __float_as_int(re[a].x)));
        re[a].y = __int_as_float(__builtin_amdgcn_ds_bpermute(bidx, __float_as_int(re[a].y)));
        im[a].x = __int_as_float(__builtin_amdgcn_ds_bpermute(bidx, __float_as_int(im[a].x)));
        im[a].y = __int_as_float(__builtin_amdgcn_ds_bpermute(bidx, __float_as_int(im[a].y)));
    }
    const bool ctl = (lane & 1) != 0;      // (5,6): ctrl lane bit0, tgt array bit 4
#pragma unroll
    for (int a = 0; a < 4; a++) {
        f2 A0 = re[a], A1 = re[a + 4], B0 = im[a], B1 = im[a + 4];
        f2 n0, n1, m0, m1;
        n0.x = ctl ? A1.x : A0.x;  n0.y = ctl ? A1.y : A0.y;
        n1.x = ctl ? A0.x : A1.x;  n1.y = ctl ? A0.y : A1.y;
        m0.x = ctl ? B1.x : B0.x;  m0.y = ctl ? B1.y : B0.y;
        m1.x = ctl ? B0.x : B1.x;  m1.y = ctl ? B0.y : B1.y;
        re[a] = n0; re[a + 4] = n1; im[a] = m0; im[a + 4] = m1;
    }
    // (6,7): ctrl array bit 4, tgt bit 2: free renames
    swapf2(re[4], re[6]); swapf2(re[5], re[7]); swapf2(im[4], im[6]); swapf2(im[5], im[7]);
    // (7,8): ctrl array bit 2, tgt bit 1
    swapf2(re[2], re[3]); swapf2(re[6], re[7]); swapf2(im[2], im[3]); swapf2(im[6], im[7]);
    // (8,9): ctrl array bit 1, tgt component
#pragma unroll
    for (int a = 1; a < 8; a += 2) { re[a] = swapc(re[a]); im[a] = swapc(im[a]); }
}

__global__ __launch_bounds__(BLOCK)
__attribute__((amdgpu_waves_per_eu(6, 8)))
void qnet_kernel(
    const float* __restrict__ x,
    const float* __restrict__ Wp,
    const float* __restrict__ bp,
    const float* __restrict__ qw,
    const float* __restrict__ Wo,
    const float* __restrict__ bo,
    float* __restrict__ out, int B)
{
    // Per-WG tables:
    __shared__ float ryt[NLAYERS * NQ * 2];            // (l*10+q)*2: cos(th/2), sin(th/2)
    __shared__ __align__(8) f2 lt[4][64];              // lane cos/sin: [0]=D_phi(0), [1+b]=boundary b
    __shared__ __align__(8) f2 vtc[3][4][8];           // boundary reg tables cos, 4 parity variants
    __shared__ __align__(8) f2 vts[3][4][8];           // boundary reg tables sin
    __shared__ __align__(8) f2 dc0[8], ds0[8];         // D_phi(0) reg table

    const int tid  = threadIdx.x;
    const int lane = tid & 63;
    const int s    = blockIdx.x * (BLOCK / 64) + (tid >> 6);   // one state per wave

    if (tid < NLAYERS * NQ) {                      // RY cos/sin pairs
        float th = qw[tid * 3 + 1];
        float sc, cc; sincosf(0.5f * th, &sc, &cc);
        ryt[tid * 2] = cc; ryt[tid * 2 + 1] = sc;
    }
    {   // lane-phase tables: 4 tables x 64 lanes = 256 entries = exactly BLOCK threads
        const int tbl = tid >> 6, ln = tid & 63;
        float ph = 0.f;
        if (tbl == 0) {                            // D_phi(0): sum_q sgn(v_q) phi_q/2, q=0..5
#pragma unroll
            for (int q = 0; q < 6; q++) {
                float a = 0.5f * qw[q * 3 + 0];
                ph += ((ln >> (5 - q)) & 1) ? a : -a;
            }
        } else {                                   // boundary b=tbl-1: omega(b) + phi(b+1) via G
            const float* qwW = qw + (size_t)(tbl - 1) * NQ * 3;
            const float* qwP = qw + (size_t)tbl * NQ * 3;
            int par = 0;
#pragma unroll
            for (int q = 0; q < 6; q++) {
                int v = (ln >> (5 - q)) & 1;
                float wa = 0.5f * qwW[q * 3 + 2];
                ph += v ? wa : -wa;                // omega: direct bit
                par ^= v;                          // par = j_q = v0^..^v_q
                if (q >= 1) {
                    float pa = 0.5f * qwP[q * 3 + 0];
                    ph += par ? pa : -pa;          // phi at permuted bit
                }
            }
        }
        float sn, cs; sincosf(ph, &sn, &cs);
        f2 e; e.x = cs; e.y = sn;
        lt[tbl][ln] = e;
    }
    if (tid < 96) {                                // boundary variant reg tables
        const int b = tid >> 5, rem = tid & 31, p = rem >> 3, a = rem & 7;
        const int pL = p >> 1, pL1 = p & 1;
        const int v6 = (a >> 2) & 1, v7 = (a >> 1) & 1, v8 = a & 1;
        const float* qwW = qw + (size_t)b * NQ * 3;        // omega layer b
        const float* qwP = qw + (size_t)(b + 1) * NQ * 3;  // phi layer b+1
        const float w6 = 0.5f * qwW[6 * 3 + 2], w7 = 0.5f * qwW[7 * 3 + 2];
        const float w8 = 0.5f * qwW[8 * 3 + 2], w9 = 0.5f * qwW[9 * 3 + 2];
        const float p0 = 0.5f * qwP[0 * 3 + 0], p6 = 0.5f * qwP[6 * 3 + 0];
        const float p7 = 0.5f * qwP[7 * 3 + 0], p8 = 0.5f * qwP[8 * 3 + 0];
        const float p9 = 0.5f * qwP[9 * 3 + 0];
        const float base = (v6 ? w6 : -w6) + (v7 ? w7 : -w7) + (v8 ? w8 : -w8);
        const int h7 = v6 ^ v7, h8 = h7 ^ v8;      // h6=v6; h8 == pR = v6^v7^v8
        const float sL  = pL  ? -1.f : 1.f;
        const float sL1 = pL1 ? -1.f : 1.f;
        const float t1b = (v6 ? p6 : -p6) + (h7 ? p7 : -p7) + (h8 ? p8 : -p8);
        float cC[2], sC[2];
#pragma unroll
        for (int C = 0; C < 2; C++) {
            float ph = base + (C ? w9 : -w9)
                     + sL  * (t1b + ((h8 ^ C) ? p9 : -p9))
                     + sL1 * ((h8 ^ C) ? p0 : -p0);
            sincosf(ph, &sC[C], &cC[C]);
        }
        f2 ec; ec.x = cC[0]; ec.y = cC[1];
        f2 es; es.x = sC[0]; es.y = sC[1];
        vtc[b][p][a] = ec; vts[b][p][a] = es;
    }
    if (tid < 8) {                                 // D_phi(0) reg table (comp-packed)
        const int a = tid;
        const int v6 = (a >> 2) & 1, v7 = (a >> 1) & 1, v8 = a & 1;
        const float p6 = 0.5f * qw[6 * 3 + 0], p7 = 0.5f * qw[7 * 3 + 0];
        const float p8 = 0.5f * qw[8 * 3 + 0], p9 = 0.5f * qw[9 * 3 + 0];
        const float base = (v6 ? p6 : -p6) + (v7 ? p7 : -p7) + (v8 ? p8 : -p8);
        float s0, c0, s1, c1;
        sincosf(base - p9, &s0, &c0);
        sincosf(base + p9, &s1, &c1);
        f2 dc; dc.x = c0; dc.y = c1;
        f2 ds; ds.x = s0; ds.y = s1;
        dc0[a] = dc; ds0[a] = ds;
    }
    __syncthreads();
    if (s >= B) return;

    // ---- projection (float4: 784 = 3*256 + 16) ----
    float acc[NQ];
#pragma unroll
    for (int q = 0; q < NQ; q++) acc[q] = 0.f;
    const float* xr = x + (size_t)s * D_IN;
#pragma unroll
    for (int it = 0; it < 3; it++) {
        const int d = (it * 64 + lane) * 4;
        float4 xv = *(const float4*)(xr + d);
#pragma unroll
        for (int q = 0; q < NQ; q++) {
            float4 wv = *(const float4*)(Wp + q * D_IN + d);
            acc[q] += xv.x * wv.x + xv.y * wv.y + xv.z * wv.z + xv.w * wv.w;
        }
    }
    if (lane < 4) {                                // tail 768..783
        const int d = (192 + lane) * 4;
        float4 xv = *(const float4*)(xr + d);
#pragma unroll
        for (int q = 0; q < NQ; q++) {
            float4 wv = *(const float4*)(Wp + q * D_IN + d);
            acc[q] += xv.x * wv.x + xv.y * wv.y + xv.z * wv.z + xv.w * wv.w;
        }
    }
#pragma unroll
    for (int q = 0; q < NQ; q++) {
#pragma unroll
        for (int o = 1; o < 64; o <<= 1) acc[q] += __shfl_xor(acc[q], o, 64);
    }
    float myc = 1.f, mys = 0.f;
    if (lane < NQ) {
        float h = tanhf(acc[lane] + bp[lane]);
        sincosf(0.5f * h, &mys, &myc);
    }

    // ---- embedding: direct product-state init (all-real, separable) ----
    f2 re[8], im[8];
    float lf = 1.f;
    {
        float cq, sq;
#define SEL(Q, MASK) cq = __shfl(myc, Q, 64); sq = __shfl(mys, Q, 64); \
                     lf *= (lane & MASK) ? sq : cq;
        SEL(0, 32) SEL(1, 16) SEL(2, 8) SEL(3, 4) SEL(4, 2) SEL(5, 1)
#undef SEL
        const float c6 = __shfl(myc, 6, 64), s6 = __shfl(mys, 6, 64);
        const float c7 = __shfl(myc, 7, 64), s7 = __shfl(mys, 7, 64);
        const float c8 = __shfl(myc, 8, 64), s8 = __shfl(mys, 8, 64);
        const float c9 = __shfl(myc, 9, 64), s9 = __shfl(mys, 9, 64);
#pragma unroll
        for (int a = 0; a < 8; a++) {
            float t = ((a & 4) ? s6 : c6) * ((a & 2) ? s7 : c7) * ((a & 1) ? s8 : c8) * lf;
            re[a].x = t * c9; re[a].y = t * s9;
            im[a] = sp(0.f);
        }
    }

    const int bidx = (lane ^ (lane >> 1)) << 2;    // Gray pull for lane CNOT chain
    const int pvar = ((__popc(lane) & 1) << 1) | (__popc(lane & 31) & 1);  // (pL, pL1)

    // ---- layer 0: D_phi(0), 10 RYs, merged boundary diag, ring ----
    {
        const float* rl = ryt;
        diag_tbl(re, im, lt[0][lane], dc0, ds0);                    // D_phi(0)
        ry_pl<32>(re, im, rl[0], rl[1]);
        ry_pl<16>(re, im, rl[2], rl[3]);
        ry_lane<8>(re, im, lane, rl[4], rl[5]);
        ry_lane<4>(re, im, lane, rl[6], rl[7]);
        ry_lane<2>(re, im, lane, rl[8], rl[9]);
        ry_lane<1>(re, im, lane, rl[10], rl[11]);
        ry_reg<4>(re, im, rl[12], rl[13]);
        ry_reg<2>(re, im, rl[14], rl[15]);
        ry_reg<1>(re, im, rl[16], rl[17]);
        ry_comp(re, im, rl[18], rl[19]);
        diag_tbl(re, im, lt[1][lane], vtc[0][pvar], vts[0][pvar]);  // = D_omega(0) + phi(1) o G
        ring(re, im, lane, bidx);                  // leaves (9,0) pending
    }

    // ---- layers 1..3 (ry0_fused consumes pending CNOT; boundary diag before ring) ----
    for (int l = 1; l < NLAYERS; l++) {
        const float* rl = ryt + l * NQ * 2;
        ry0_fused(re, im, rl[0], rl[1]);           // consumes pending C (phi already applied)
        ry_pl<16>(re, im, rl[2], rl[3]);
        ry_lane<8>(re, im, lane, rl[4], rl[5]);
        ry_lane<4>(re, im, lane, rl[6], rl[7]);
        ry_lane<2>(re, im, lane, rl[8], rl[9]);
        ry_lane<1>(re, im, lane, rl[10], rl[11]);
        ry_reg<4>(re, im, rl[12], rl[13]);
        ry_reg<2>(re, im, rl[14], rl[15]);
        ry_reg<1>(re, im, rl[16], rl[17]);
        ry_comp(re, im, rl[18], rl[19]);
        if (l < NLAYERS - 1)                       // merged boundary diag l (omega(l)+phi(l+1)oG)
            diag_tbl(re, im, lt[l + 1][lane], vtc[l][pvar], vts[l][pvar]);
        ring(re, im, lane, bidx);                  // (9,0) pending again
    }
    // Final pending (9,0) CNOT folded into measurement sign masks below.
    // (Last layer's D_omega skipped: diagonals don't change |amp|^2.)

    // ---- measurement: Z expectation per qubit ----
    f2 S2 = {0.f, 0.f}, z62 = {0.f, 0.f}, z72 = {0.f, 0.f}, z82 = {0.f, 0.f};
#pragma unroll
    for (int a = 0; a < 8; a++) {
        f2 p = re[a] * re[a] + im[a] * im[a];
        S2 += p;
        if (a & 4) z62 -= p; else z62 += p;
        if (a & 2) z72 -= p; else z72 += p;
        if (a & 1) z82 -= p; else z82 += p;
    }
    const float Ssum = S2.x + S2.y;
    const float Sdif = S2.x - S2.y;
    float zq[NQ];
    zq[0] = (lane & 32) ? -Sdif : Sdif;   // q0: lane bit32 XOR component (folded CNOT)
    zq[1] = (lane & 16) ? -Ssum : Ssum;
    zq[2] = (lane &  8) ? -Ssum : Ssum;
    zq[3] = (lane &  4) ? -Ssum : Ssum;
    zq[4] = (lane &  2) ? -Ssum : Ssum;
    zq[5] = (lane &  1) ? -Ssum : Ssum;
    zq[6] = z62.x + z62.y;
    zq[7] = z72.x + z72.y;
    zq[8] = z82.x + z82.y;
    zq[9] = Sdif;                          // q9: component bit (untouched by folded CNOT)
#pragma unroll
    for (int q = 0; q < NQ; q++) {
#pragma unroll
        for (int o = 1; o < 64; o <<= 1) zq[q] += __shfl_xor(zq[q], o, 64);
    }

    // ---- output projection: out = zq @ Wo^T + bo ----
    if (lane < NQ) {
        const float* wrow = Wo + lane * NQ;
        float o0 = bo[lane];
#pragma unroll
        for (int q = 0; q < NQ; q++) o0 += zq[q] * wrow[q];
        out[(size_t)s * NQ + lane] = o0;
    }
}

extern "C" void kernel_launch(void* const* d_in, const int* in_sizes, int n_in,
                              void* d_out, int out_size, void* d_ws, size_t ws_size,
                              hipStream_t stream) {
    const float* x  = (const float*)d_in[0];
    const float* Wp = (const float*)d_in[1];
    const float* bp = (const float*)d_in[2];
    const float* qw = (const float*)d_in[3];
    const float* Wo = (const float*)d_in[4];
    const float* bo = (const float*)d_in[5];
    float* out = (float*)d_out;

    const int B = in_sizes[0] / D_IN;                  // 8192 states, one per wave
    const int spb = BLOCK / 64;                        // states per block (4)
    const int blocks = (B + spb - 1) / spb;
    hipLaunchKernelGGL(qnet_kernel, dim3(blocks), dim3(BLOCK), 0, stream,
                       x, Wp, bp, qw, Wo, bo, out, B);
}

// Round 12
// 135.570 us; speedup vs baseline: 1.0553x; 1.0553x over previous
//
#include <hip/hip_runtime.h>

#define NQ      10
#define NLAYERS 4
#define D_IN    784
#define BLOCK   256   // 4 waves per workgroup, ONE state per wave, amp-pair pk packing.
// R25: FINAL — exact revert to R23 (best measured: 76.9us dispatch / 135.7us bench).
// R24's (6,8) probe closed the residency question: allocator grants {min=8:32, 6:40,
// 5:48, <=4:64} regs — 64 is BOTH the kernel's appetite and the max grant at any min<=4,
// so no knob raises residency without forcing a spill (R24: VGPR 40, 37.8MB scratch,
// 83us). The ~34% occupancy plateau under (2,8) is dispatch/tail behavior of a short
// 4-wave-WG kernel, not registers. Session ledger: stream-length cuts took 114->77us
// (pk packing -14%, Rot=D*RY*D factorization -10%, merged boundary diagonals -6%);
// every scheduling/residency intervention (R13/R19/R20/R21/R24) was neutral-to-negative.
// Remaining: ~51us irreducible VALU stream at 67% busy; HBM 2%; bank conflicts 0.
// KEEP (2,8). Do not re-tune waves_per_eu; do not re-introduce asm-pk or rfl hoists.
// R23 structure: merged boundary diagonals D_phi(l+1) o Ring o D_omega(l) = Ring o D'
// (G = ring bit-map incl. deferred CNOT(9,0): v'_q = v0^..^v_q (q>=1), v'_0 = v1^..^v9)
// with 64-entry LDS lane trig + 4-parity-variant reg tables; in-loop sincos = 0;
// Rot = D_omega * RY * D_phi factorization; real RY gates; last D_omega skipped;
// embedding = product-state init; ring CNOT(9,0) folded into ry0_fused / measurement.
// LOCKED: reductions use plain __shfl_xor only (R8 DPP reductions diverged across graph
// replays). DPP confined to full-exec lane exchanges (stable since R4).

// Amplitude index i (10 bits): lane bits 9..4 (q0..q5 = lane&32..lane&1),
// array-index bits 3..1 (q6,q7,q8 = a&4,a&2,a&1), component bit 0 (q9 = f2 comp).

typedef __attribute__((ext_vector_type(2))) float f2;

__device__ __forceinline__ f2 sp(float v) { f2 r; r.x = v; r.y = v; return r; }
__device__ __forceinline__ f2 swapc(f2 v) { return __builtin_shufflevector(v, v, 1, 0); }

// ---- lane exchange: xor LB, VALU pipe where possible ----
template<int LB>
__device__ __forceinline__ float lx(float v) {
    if constexpr (LB == 1) {        // quad_perm [1,0,3,2]
        return __int_as_float(__builtin_amdgcn_update_dpp(
            0, __float_as_int(v), 0xB1, 0xF, 0xF, false));
    } else if constexpr (LB == 2) { // quad_perm [2,3,0,1]
        return __int_as_float(__builtin_amdgcn_update_dpp(
            0, __float_as_int(v), 0x4E, 0xF, 0xF, false));
    } else if constexpr (LB == 8) { // row_ror:8 within 16 == xor 8 (VALU)
        return __int_as_float(__builtin_amdgcn_update_dpp(
            0, __float_as_int(v), 0x128, 0xF, 0xF, false));
    } else {
        return __shfl_xor(v, LB, 64);   // LB==4: DS pipe (no VALU equivalent)
    }
}

template<int LB>
__device__ __forceinline__ f2 lx2(f2 v) {
    f2 r; r.x = lx<LB>(v.x); r.y = lx<LB>(v.y); return r;
}

// ---- permlane pair swap (VALU pipe) ----
template<int HALF>
__device__ __forceinline__ void plswap(f2 &d, f2 &s) {
    if constexpr (HALF == 32) {
        auto rx = __builtin_amdgcn_permlane32_swap(__float_as_int(d.x), __float_as_int(s.x), false, false);
        auto ry = __builtin_amdgcn_permlane32_swap(__float_as_int(d.y), __float_as_int(s.y), false, false);
        d.x = __int_as_float(rx[0]); s.x = __int_as_float(rx[1]);
        d.y = __int_as_float(ry[0]); s.y = __int_as_float(ry[1]);
    } else {
        auto rx = __builtin_amdgcn_permlane16_swap(__float_as_int(d.x), __float_as_int(s.x), false, false);
        auto ry = __builtin_amdgcn_permlane16_swap(__float_as_int(d.y), __float_as_int(s.y), false, false);
        d.x = __int_as_float(rx[0]); s.x = __int_as_float(rx[1]);
        d.y = __int_as_float(ry[0]); s.y = __int_as_float(ry[1]);
    }
}

// ---- real RY on lane bit 32/16 via permlane pair-processing ----
template<int HALF>
__device__ __forceinline__ void ry_pl(f2 (&re)[8], f2 (&im)[8], float c, float s) {
#pragma unroll
    for (int a = 0; a < 8; a += 2) {
        f2 ur = re[a], vr = re[a + 1], ui = im[a], vi = im[a + 1];
        plswap<HALF>(ur, vr); plswap<HALF>(ui, vi);
        f2 nur = sp(c)*ur - sp(s)*vr;   f2 nui = sp(c)*ui - sp(s)*vi;
        f2 nvr = sp(s)*ur + sp(c)*vr;   f2 nvi = sp(s)*ui + sp(c)*vi;
        plswap<HALF>(nur, nvr); plswap<HALF>(nui, nvi);
        re[a] = nur; re[a + 1] = nvr; im[a] = nui; im[a + 1] = nvi;
    }
}

// ---- real RY on q0 (lane bit 32) with pending CNOT(ctrl=comp, tgt=bit32) consumed. ----
__device__ __forceinline__ void ry0_fused(f2 (&re)[8], f2 (&im)[8], float c, float s) {
    f2 K1, K2, K3, K4;
    K1.x =  c; K1.y = -s;   K2.x = -s; K2.y =  c;
    K3.x =  s; K3.y =  c;   K4.x =  c; K4.y =  s;
#pragma unroll
    for (int a = 0; a < 8; a += 2) {
        f2 ur = re[a], vr = re[a + 1], ui = im[a], vi = im[a + 1];
        plswap<32>(ur, vr); plswap<32>(ui, vi);
        f2 nur = K1*ur + K2*vr;   f2 nui = K1*ui + K2*vi;
        f2 nvr = K3*ur + K4*vr;   f2 nvi = K3*ui + K4*vi;
        plswap<32>(nur, nvr); plswap<32>(nui, nvi);
        re[a] = nur; re[a + 1] = nvr; im[a] = nui; im[a + 1] = nvi;
    }
}

// ---- real RY on lane bit LB (8,4,2,1): exchange + 4 pk per reg ----
template<int LB>
__device__ __forceinline__ void ry_lane(f2 (&re)[8], f2 (&im)[8], int lane, float c, float s) {
    const float o = (lane & LB) ? s : -s;   // lo: u' = c*u - s*v ; hi: v' = c*v + s*u
#pragma unroll
    for (int a = 0; a < 8; a++) {
        f2 ore = lx2<LB>(re[a]);
        f2 oim = lx2<LB>(im[a]);
        re[a] = sp(c)*re[a] + sp(o)*ore;
        im[a] = sp(c)*im[a] + sp(o)*oim;
    }
}

// ---- real RY on array-index bit MB (4,2,1): 8 pk per pair ----
template<int MB>
__device__ __forceinline__ void ry_reg(f2 (&re)[8], f2 (&im)[8], float c, float s) {
#pragma unroll
    for (int a = 0; a < 8; a++) {
        if (!(a & MB)) {
            const int a1 = a | MB;
            f2 r0 = re[a], r1 = re[a1], i0 = im[a], i1 = im[a1];
            re[a]  = sp(c)*r0 - sp(s)*r1;   re[a1] = sp(s)*r0 + sp(c)*r1;
            im[a]  = sp(c)*i0 - sp(s)*i1;   im[a1] = sp(s)*i0 + sp(c)*i1;
        }
    }
}

// ---- real RY on the component bit (q9): swapc + 4 pk per reg ----
__device__ __forceinline__ void ry_comp(f2 (&re)[8], f2 (&im)[8], float c, float s) {
    f2 Ks; Ks.x = -s; Ks.y = s;
#pragma unroll
    for (int a = 0; a < 8; a++) {
        f2 sre = swapc(re[a]), sim = swapc(im[a]);
        re[a] = sp(c)*re[a] + Ks*sre;
        im[a] = sp(c)*im[a] + Ks*sim;
    }
}

// ---- table-driven diagonal: factor = e^{i*lane_phase} * e^{i*table_phase[a]}.
// lp = (cos,sin) of the lane phase (from LDS); DC/DS = cos/sin reg tables (comp-packed).
__device__ __forceinline__ void diag_tbl(f2 (&re)[8], f2 (&im)[8], f2 lp,
                                         const f2* DC, const f2* DS) {
    f2 cl = sp(lp.x), sl = sp(lp.y);
#pragma unroll
    for (int a = 0; a < 8; a++) {
        f2 cr = cl*DC[a] - sl*DS[a];      // cos(lane+table)
        f2 ci = cl*DS[a] + sl*DC[a];      // sin(lane+table)
        f2 nr = cr*re[a] - ci*im[a];
        f2 ni = cr*im[a] + ci*re[a];
        re[a] = nr; im[a] = ni;
    }
}

__device__ __forceinline__ void swapf2(f2 &a, f2 &b) { f2 t = a; a = b; b = t; }

// ---- CNOT ring: Gray bpermute (q0..q5 chain), (5,6) cndmask, renames, (8,9) comp swap.
// (9,0) NOT applied: folded into next layer's ry0_fused or measurement signs. ----
__device__ __forceinline__ void ring(f2 (&re)[8], f2 (&im)[8], int lane, int bidx) {
#pragma unroll
    for (int a = 0; a < 8; a++) {
        re[a].x = __int_as_float(__builtin_amdgcn_ds_bpermute(bidx, __float_as_int(re[a].x)));
        re[a].y = __int_as_float(__builtin_amdgcn_ds_bpermute(bidx, __float_as_int(re[a].y)));
        im[a].x = __int_as_float(__builtin_amdgcn_ds_bpermute(bidx, __float_as_int(im[a].x)));
        im[a].y = __int_as_float(__builtin_amdgcn_ds_bpermute(bidx, __float_as_int(im[a].y)));
    }
    const bool ctl = (lane & 1) != 0;      // (5,6): ctrl lane bit0, tgt array bit 4
#pragma unroll
    for (int a = 0; a < 4; a++) {
        f2 A0 = re[a], A1 = re[a + 4], B0 = im[a], B1 = im[a + 4];
        f2 n0, n1, m0, m1;
        n0.x = ctl ? A1.x : A0.x;  n0.y = ctl ? A1.y : A0.y;
        n1.x = ctl ? A0.x : A1.x;  n1.y = ctl ? A0.y : A1.y;
        m0.x = ctl ? B1.x : B0.x;  m0.y = ctl ? B1.y : B0.y;
        m1.x = ctl ? B0.x : B1.x;  m1.y = ctl ? B0.y : B1.y;
        re[a] = n0; re[a + 4] = n1; im[a] = m0; im[a + 4] = m1;
    }
    // (6,7): ctrl array bit 4, tgt bit 2: free renames
    swapf2(re[4], re[6]); swapf2(re[5], re[7]); swapf2(im[4], im[6]); swapf2(im[5], im[7]);
    // (7,8): ctrl array bit 2, tgt bit 1
    swapf2(re[2], re[3]); swapf2(re[6], re[7]); swapf2(im[2], im[3]); swapf2(im[6], im[7]);
    // (8,9): ctrl array bit 1, tgt component
#pragma unroll
    for (int a = 1; a < 8; a += 2) { re[a] = swapc(re[a]); im[a] = swapc(im[a]); }
}

__global__ __launch_bounds__(BLOCK)
__attribute__((amdgpu_waves_per_eu(2, 8)))
void qnet_kernel(
    const float* __restrict__ x,
    const float* __restrict__ Wp,
    const float* __restrict__ bp,
    const float* __restrict__ qw,
    const float* __restrict__ Wo,
    const float* __restrict__ bo,
    float* __restrict__ out, int B)
{
    // Per-WG tables:
    __shared__ float ryt[NLAYERS * NQ * 2];            // (l*10+q)*2: cos(th/2), sin(th/2)
    __shared__ __align__(8) f2 lt[4][64];              // lane cos/sin: [0]=D_phi(0), [1+b]=boundary b
    __shared__ __align__(8) f2 vtc[3][4][8];           // boundary reg tables cos, 4 parity variants
    __shared__ __align__(8) f2 vts[3][4][8];           // boundary reg tables sin
    __shared__ __align__(8) f2 dc0[8], ds0[8];         // D_phi(0) reg table

    const int tid  = threadIdx.x;
    const int lane = tid & 63;
    const int s    = blockIdx.x * (BLOCK / 64) + (tid >> 6);   // one state per wave

    if (tid < NLAYERS * NQ) {                      // RY cos/sin pairs
        float th = qw[tid * 3 + 1];
        float sc, cc; sincosf(0.5f * th, &sc, &cc);
        ryt[tid * 2] = cc; ryt[tid * 2 + 1] = sc;
    }
    {   // lane-phase tables: 4 tables x 64 lanes = 256 entries = exactly BLOCK threads
        const int tbl = tid >> 6, ln = tid & 63;
        float ph = 0.f;
        if (tbl == 0) {                            // D_phi(0): sum_q sgn(v_q) phi_q/2, q=0..5
#pragma unroll
            for (int q = 0; q < 6; q++) {
                float a = 0.5f * qw[q * 3 + 0];
                ph += ((ln >> (5 - q)) & 1) ? a : -a;
            }
        } else {                                   // boundary b=tbl-1: omega(b) + phi(b+1) via G
            const float* qwW = qw + (size_t)(tbl - 1) * NQ * 3;
            const float* qwP = qw + (size_t)tbl * NQ * 3;
            int par = 0;
#pragma unroll
            for (int q = 0; q < 6; q++) {
                int v = (ln >> (5 - q)) & 1;
                float wa = 0.5f * qwW[q * 3 + 2];
                ph += v ? wa : -wa;                // omega: direct bit
                par ^= v;                          // par = j_q = v0^..^v_q
                if (q >= 1) {
                    float pa = 0.5f * qwP[q * 3 + 0];
                    ph += par ? pa : -pa;          // phi at permuted bit
                }
            }
        }
        float sn, cs; sincosf(ph, &sn, &cs);
        f2 e; e.x = cs; e.y = sn;
        lt[tbl][ln] = e;
    }
    if (tid < 96) {                                // boundary variant reg tables
        const int b = tid >> 5, rem = tid & 31, p = rem >> 3, a = rem & 7;
        const int pL = p >> 1, pL1 = p & 1;
        const int v6 = (a >> 2) & 1, v7 = (a >> 1) & 1, v8 = a & 1;
        const float* qwW = qw + (size_t)b * NQ * 3;        // omega layer b
        const float* qwP = qw + (size_t)(b + 1) * NQ * 3;  // phi layer b+1
        const float w6 = 0.5f * qwW[6 * 3 + 2], w7 = 0.5f * qwW[7 * 3 + 2];
        const float w8 = 0.5f * qwW[8 * 3 + 2], w9 = 0.5f * qwW[9 * 3 + 2];
        const float p0 = 0.5f * qwP[0 * 3 + 0], p6 = 0.5f * qwP[6 * 3 + 0];
        const float p7 = 0.5f * qwP[7 * 3 + 0], p8 = 0.5f * qwP[8 * 3 + 0];
        const float p9 = 0.5f * qwP[9 * 3 + 0];
        const float base = (v6 ? w6 : -w6) + (v7 ? w7 : -w7) + (v8 ? w8 : -w8);
        const int h7 = v6 ^ v7, h8 = h7 ^ v8;      // h6=v6; h8 == pR = v6^v7^v8
        const float sL  = pL  ? -1.f : 1.f;
        const float sL1 = pL1 ? -1.f : 1.f;
        const float t1b = (v6 ? p6 : -p6) + (h7 ? p7 : -p7) + (h8 ? p8 : -p8);
        float cC[2], sC[2];
#pragma unroll
        for (int C = 0; C < 2; C++) {
            float ph = base + (C ? w9 : -w9)
                     + sL  * (t1b + ((h8 ^ C) ? p9 : -p9))
                     + sL1 * ((h8 ^ C) ? p0 : -p0);
            sincosf(ph, &sC[C], &cC[C]);
        }
        f2 ec; ec.x = cC[0]; ec.y = cC[1];
        f2 es; es.x = sC[0]; es.y = sC[1];
        vtc[b][p][a] = ec; vts[b][p][a] = es;
    }
    if (tid < 8) {                                 // D_phi(0) reg table (comp-packed)
        const int a = tid;
        const int v6 = (a >> 2) & 1, v7 = (a >> 1) & 1, v8 = a & 1;
        const float p6 = 0.5f * qw[6 * 3 + 0], p7 = 0.5f * qw[7 * 3 + 0];
        const float p8 = 0.5f * qw[8 * 3 + 0], p9 = 0.5f * qw[9 * 3 + 0];
        const float base = (v6 ? p6 : -p6) + (v7 ? p7 : -p7) + (v8 ? p8 : -p8);
        float s0, c0, s1, c1;
        sincosf(base - p9, &s0, &c0);
        sincosf(base + p9, &s1, &c1);
        f2 dc; dc.x = c0; dc.y = c1;
        f2 ds; ds.x = s0; ds.y = s1;
        dc0[a] = dc; ds0[a] = ds;
    }
    __syncthreads();
    if (s >= B) return;

    // ---- projection (float4: 784 = 3*256 + 16) ----
    float acc[NQ];
#pragma unroll
    for (int q = 0; q < NQ; q++) acc[q] = 0.f;
    const float* xr = x + (size_t)s * D_IN;
#pragma unroll
    for (int it = 0; it < 3; it++) {
        const int d = (it * 64 + lane) * 4;
        float4 xv = *(const float4*)(xr + d);
#pragma unroll
        for (int q = 0; q < NQ; q++) {
            float4 wv = *(const float4*)(Wp + q * D_IN + d);
            acc[q] += xv.x * wv.x + xv.y * wv.y + xv.z * wv.z + xv.w * wv.w;
        }
    }
    if (lane < 4) {                                // tail 768..783
        const int d = (192 + lane) * 4;
        float4 xv = *(const float4*)(xr + d);
#pragma unroll
        for (int q = 0; q < NQ; q++) {
            float4 wv = *(const float4*)(Wp + q * D_IN + d);
            acc[q] += xv.x * wv.x + xv.y * wv.y + xv.z * wv.z + xv.w * wv.w;
        }
    }
#pragma unroll
    for (int q = 0; q < NQ; q++) {
#pragma unroll
        for (int o = 1; o < 64; o <<= 1) acc[q] += __shfl_xor(acc[q], o, 64);
    }
    float myc = 1.f, mys = 0.f;
    if (lane < NQ) {
        float h = tanhf(acc[lane] + bp[lane]);
        sincosf(0.5f * h, &mys, &myc);
    }

    // ---- embedding: direct product-state init (all-real, separable) ----
    f2 re[8], im[8];
    float lf = 1.f;
    {
        float cq, sq;
#define SEL(Q, MASK) cq = __shfl(myc, Q, 64); sq = __shfl(mys, Q, 64); \
                     lf *= (lane & MASK) ? sq : cq;
        SEL(0, 32) SEL(1, 16) SEL(2, 8) SEL(3, 4) SEL(4, 2) SEL(5, 1)
#undef SEL
        const float c6 = __shfl(myc, 6, 64), s6 = __shfl(mys, 6, 64);
        const float c7 = __shfl(myc, 7, 64), s7 = __shfl(mys, 7, 64);
        const float c8 = __shfl(myc, 8, 64), s8 = __shfl(mys, 8, 64);
        const float c9 = __shfl(myc, 9, 64), s9 = __shfl(mys, 9, 64);
#pragma unroll
        for (int a = 0; a < 8; a++) {
            float t = ((a & 4) ? s6 : c6) * ((a & 2) ? s7 : c7) * ((a & 1) ? s8 : c8) * lf;
            re[a].x = t * c9; re[a].y = t * s9;
            im[a] = sp(0.f);
        }
    }

    const int bidx = (lane ^ (lane >> 1)) << 2;    // Gray pull for lane CNOT chain
    const int pvar = ((__popc(lane) & 1) << 1) | (__popc(lane & 31) & 1);  // (pL, pL1)

    // ---- layer 0: D_phi(0), 10 RYs, merged boundary diag, ring ----
    {
        const float* rl = ryt;
        diag_tbl(re, im, lt[0][lane], dc0, ds0);                    // D_phi(0)
        ry_pl<32>(re, im, rl[0], rl[1]);
        ry_pl<16>(re, im, rl[2], rl[3]);
        ry_lane<8>(re, im, lane, rl[4], rl[5]);
        ry_lane<4>(re, im, lane, rl[6], rl[7]);
        ry_lane<2>(re, im, lane, rl[8], rl[9]);
        ry_lane<1>(re, im, lane, rl[10], rl[11]);
        ry_reg<4>(re, im, rl[12], rl[13]);
        ry_reg<2>(re, im, rl[14], rl[15]);
        ry_reg<1>(re, im, rl[16], rl[17]);
        ry_comp(re, im, rl[18], rl[19]);
        diag_tbl(re, im, lt[1][lane], vtc[0][pvar], vts[0][pvar]);  // = D_omega(0) + phi(1) o G
        ring(re, im, lane, bidx);                  // leaves (9,0) pending
    }

    // ---- layers 1..3 (ry0_fused consumes pending CNOT; boundary diag before ring) ----
    for (int l = 1; l < NLAYERS; l++) {
        const float* rl = ryt + l * NQ * 2;
        ry0_fused(re, im, rl[0], rl[1]);           // consumes pending C (phi already applied)
        ry_pl<16>(re, im, rl[2], rl[3]);
        ry_lane<8>(re, im, lane, rl[4], rl[5]);
        ry_lane<4>(re, im, lane, rl[6], rl[7]);
        ry_lane<2>(re, im, lane, rl[8], rl[9]);
        ry_lane<1>(re, im, lane, rl[10], rl[11]);
        ry_reg<4>(re, im, rl[12], rl[13]);
        ry_reg<2>(re, im, rl[14], rl[15]);
        ry_reg<1>(re, im, rl[16], rl[17]);
        ry_comp(re, im, rl[18], rl[19]);
        if (l < NLAYERS - 1)                       // merged boundary diag l (omega(l)+phi(l+1)oG)
            diag_tbl(re, im, lt[l + 1][lane], vtc[l][pvar], vts[l][pvar]);
        ring(re, im, lane, bidx);                  // (9,0) pending again
    }
    // Final pending (9,0) CNOT folded into measurement sign masks below.
    // (Last layer's D_omega skipped: diagonals don't change |amp|^2.)

    // ---- measurement: Z expectation per qubit ----
    f2 S2 = {0.f, 0.f}, z62 = {0.f, 0.f}, z72 = {0.f, 0.f}, z82 = {0.f, 0.f};
#pragma unroll
    for (int a = 0; a < 8; a++) {
        f2 p = re[a] * re[a] + im[a] * im[a];
        S2 += p;
        if (a & 4) z62 -= p; else z62 += p;
        if (a & 2) z72 -= p; else z72 += p;
        if (a & 1) z82 -= p; else z82 += p;
    }
    const float Ssum = S2.x + S2.y;
    const float Sdif = S2.x - S2.y;
    float zq[NQ];
    zq[0] = (lane & 32) ? -Sdif : Sdif;   // q0: lane bit32 XOR component (folded CNOT)
    zq[1] = (lane & 16) ? -Ssum : Ssum;
    zq[2] = (lane &  8) ? -Ssum : Ssum;
    zq[3] = (lane &  4) ? -Ssum : Ssum;
    zq[4] = (lane &  2) ? -Ssum : Ssum;
    zq[5] = (lane &  1) ? -Ssum : Ssum;
    zq[6] = z62.x + z62.y;
    zq[7] = z72.x + z72.y;
    zq[8] = z82.x + z82.y;
    zq[9] = Sdif;                          // q9: component bit (untouched by folded CNOT)
#pragma unroll
    for (int q = 0; q < NQ; q++) {
#pragma unroll
        for (int o = 1; o < 64; o <<= 1) zq[q] += __shfl_xor(zq[q], o, 64);
    }

    // ---- output projection: out = zq @ Wo^T + bo ----
    if (lane < NQ) {
        const float* wrow = Wo + lane * NQ;
        float o0 = bo[lane];
#pragma unroll
        for (int q = 0; q < NQ; q++) o0 += zq[q] * wrow[q];
        out[(size_t)s * NQ + lane] = o0;
    }
}

extern "C" void kernel_launch(void* const* d_in, const int* in_sizes, int n_in,
                              void* d_out, int out_size, void* d_ws, size_t ws_size,
                              hipStream_t stream) {
    const float* x  = (const float*)d_in[0];
    const float* Wp = (const float*)d_in[1];
    const float* bp = (const float*)d_in[2];
    const float* qw = (const float*)d_in[3];
    const float* Wo = (const float*)d_in[4];
    const float* bo = (const float*)d_in[5];
    float* out = (float*)d_out;

    const int B = in_sizes[0] / D_IN;                  // 8192 states, one per wave
    const int spb = BLOCK / 64;                        // states per block (4)
    const int blocks = (B + spb - 1) / spb;
    hipLaunchKernelGGL(qnet_kernel, dim3(blocks), dim3(BLOCK), 0, stream,
                       x, Wp, bp, qw, Wo, bo, out, B);
}